// Round 10
// baseline (3587.981 us; speedup 1.0000x reference)
//
#include <hip/hip_runtime.h>

typedef unsigned short u16t;
typedef __attribute__((ext_vector_type(4))) float f32x4;

#define DI static __device__ __forceinline__

constexpr int Bn = 256, Tn = 512;
constexpr long Rn = (long)Bn * Tn;   // 131072 rows = (b,t) pairs

DI float b2f(u16t u){ union{unsigned u32; float f;} v; v.u32 = ((unsigned)u)<<16; return v.f; }
DI u16t f2b(float f){ union{float fp; unsigned u;} v; v.fp=f; return (u16t)((v.u + 0x7fffu + ((v.u>>16)&1u))>>16); }
DI float fsigm(float x){ return __builtin_amdgcn_rcpf(1.f + __expf(-x)); }
DI float fgelu(float x){
  float t = 0.7978845608028654f*x*(1.f + 0.044715f*x*x);
  return x*(1.f - __builtin_amdgcn_rcpf(__expf(2.f*t)+1.f));
}
DI float ftanh(float x){ float e = __expf(2.f*x); return 1.f - 2.f*__builtin_amdgcn_rcpf(e+1.f); }

// ---------------- K1: parallel pre-pass, PURE VALU ----------------
// zfn (fp32) = f_mean + exp(.5 f_lv)*nf ; se1s (bf16) = state @ se_w1[:, :256]^T + se_b1
__global__ __launch_bounds__(256) void k_pre(
    const float* __restrict__ states, const float* __restrict__ nfast,
    const float* __restrict__ fe_w1, const float* __restrict__ fe_b1,
    const float* __restrict__ fe_w2, const float* __restrict__ fe_b2,
    const float* __restrict__ se_w1, const float* __restrict__ se_b1,
    float* __restrict__ ws_zfn, u16t* __restrict__ ws_se1)
{
  __shared__ float xs[16][256];
  __shared__ float hs[16][256];
  __shared__ float fps[16][64];
  const int tid = threadIdx.x;
  const long row0 = (long)blockIdx.x * 16;

  {
    int r = tid >> 4, k0 = (tid & 15) * 16;
    #pragma unroll
    for (int j=0;j<16;j+=4)
      *(f32x4*)&xs[r][k0+j] = *(const f32x4*)(states + (row0+r)*256 + k0 + j);
  }
  __syncthreads();

  {
    const int n = tid;
    const bool dose = (n < 128);
    float a1[16], a3[16];
    const float b1v = fe_b1[n];
    #pragma unroll
    for (int r=0;r<16;r++) a1[r] = b1v;
    if (dose){
      const float b3v = se_b1[n];
      #pragma unroll
      for (int r=0;r<16;r++) a3[r] = b3v;
      for (int k=0;k<256;k+=4){
        f32x4 w1 = *(const f32x4*)(fe_w1 + n*256 + k);
        f32x4 w2 = *(const f32x4*)(se_w1 + n*288 + k);
        #pragma unroll
        for (int j=0;j<4;j++){
          #pragma unroll
          for (int r=0;r<16;r++){
            float xv = xs[r][k+j];
            a1[r] += w1[j]*xv;
            a3[r] += w2[j]*xv;
          }
        }
      }
      #pragma unroll
      for (int r=0;r<16;r++) ws_se1[(row0+r)*128 + n] = f2b(a3[r]);
    } else {
      for (int k=0;k<256;k+=4){
        f32x4 w1 = *(const f32x4*)(fe_w1 + n*256 + k);
        #pragma unroll
        for (int j=0;j<4;j++){
          #pragma unroll
          for (int r=0;r<16;r++) a1[r] += w1[j]*xs[r][k+j];
        }
      }
    }
    #pragma unroll
    for (int r=0;r<16;r++) hs[r][n] = fgelu(a1[r]);
  }
  __syncthreads();

  {
    const int n = tid & 63, rh = tid >> 6;
    float a2[4];
    const float b2v = fe_b2[n];
    #pragma unroll
    for (int r=0;r<4;r++) a2[r] = b2v;
    for (int k=0;k<256;k+=4){
      f32x4 w = *(const f32x4*)(fe_w2 + n*256 + k);
      #pragma unroll
      for (int j=0;j<4;j++){
        #pragma unroll
        for (int r=0;r<4;r++) a2[r] += w[j]*hs[rh*4+r][k+j];
      }
    }
    #pragma unroll
    for (int r=0;r<4;r++) fps[rh*4+r][n] = a2[r];
  }
  __syncthreads();

  {
    int r = tid >> 4, c = (tid & 15) * 2;
    #pragma unroll
    for (int q=0;q<2;q++){
      int col = c + q;
      float nfv = nfast[(row0+r)*32 + col];
      float zv = fps[r][col] + __expf(0.5f*fps[r][col+32])*nfv;
      ws_zfn[(row0+r)*32 + col] = zv;
    }
  }
}

// ---------------- K2: recurrence — fp32-exact, weights in LDS ----------------
__global__ __launch_bounds__(64,1) void k_rec(
  const float* __restrict__ ws_zfn, const u16t* __restrict__ ws_se1,
  const float* __restrict__ actions, const float* __restrict__ noise_slow,
  const float* __restrict__ fg_wih, const float* __restrict__ fg_whh,
  const float* __restrict__ fg_bih, const float* __restrict__ fg_bhh,
  const float* __restrict__ se_w1, const float* __restrict__ se_w2, const float* __restrict__ se_b2,
  const float* __restrict__ sg_wih, const float* __restrict__ sg_whh,
  const float* __restrict__ sg_bih, const float* __restrict__ sg_bhh,
  const float* __restrict__ updp,
  float* __restrict__ out_zf, float* __restrict__ out_zs)
{
  __shared__ float Wgi[96*36], Wgh[96*32], bgi[96], bgh[96];
  __shared__ float Wse[128*32];
  __shared__ float Wsp[32*128], bsp[32];
  __shared__ float Wsg[48*48], Wsh[48*16], bsg[48], bsh[48];
  __shared__ float zfv[32], zsv[16], zfnv[32], actv[4], nsv[16];
  __shared__ float se1v[128], hidv[128], zsnv[16];
  __shared__ float giv[96], ghv[96], spv[32], sgiv[48], sghv[48];
  const int lane = threadIdx.x;
  const long base = (long)blockIdx.x * Tn;

  for (int i=lane;i<96*36;i+=64) Wgi[i]=fg_wih[i];
  for (int i=lane;i<96*32;i+=64) Wgh[i]=fg_whh[i];
  for (int i=lane;i<96;i+=64){ bgi[i]=fg_bih[i]; bgh[i]=fg_bhh[i]; }
  for (int i=lane;i<128*32;i+=64) Wse[i]=se_w1[(i>>5)*288 + 256 + (i&31)];
  for (int i=lane;i<32*128;i+=64) Wsp[i]=se_w2[i];
  for (int i=lane;i<32;i+=64) bsp[i]=se_b2[i];
  for (int i=lane;i<48*48;i+=64) Wsg[i]=sg_wih[i];
  for (int i=lane;i<48*16;i+=64) Wsh[i]=sg_whh[i];
  for (int i=lane;i<48;i+=64){ bsg[i]=sg_bih[i]; bsh[i]=sg_bhh[i]; }
  const float upd = fsigm(updp[0]);
  if (lane<32) zfv[lane]=0.f;
  if (lane<16) zsv[lane]=0.f;

  float pzfn=0.f, pact=0.f, pns=0.f; u16t ps0=0, ps1=0;
  auto pf=[&](int tt){
    if (lane<32) pzfn = ws_zfn[(base+tt)*32+lane];
    ps0 = ws_se1[(base+tt)*128+lane]; ps1 = ws_se1[(base+tt)*128+64+lane];
    if (lane<4) pact = actions[(base+tt)*4+lane];
    if (lane<16) pns = noise_slow[(base+tt)*16+lane];
  };
  pf(0);
  __syncthreads();

  for (int t=0;t<Tn;t++){
    if (lane<32) zfnv[lane]=pzfn;
    se1v[lane]=b2f(ps0); se1v[64+lane]=b2f(ps1);
    if (lane<4) actv[lane]=pact;
    if (lane<16) nsv[lane]=pns;
    __syncthreads();
    if (t+1<Tn) pf(t+1);

    // P1: fast-GRU gate pre-activations
    {
      float si = bgi[lane], sh = bgh[lane];
      #pragma unroll 8
      for (int k=0;k<32;k++){ si += Wgi[lane*36+k]*zfnv[k]; sh += Wgh[lane*32+k]*zfv[k]; }
      #pragma unroll
      for (int k=0;k<4;k++) si += Wgi[lane*36+32+k]*actv[k];
      giv[lane]=si; ghv[lane]=sh;
      if (lane<32){
        int o=64+lane; float si2=bgi[o], sh2=bgh[o];
        #pragma unroll 8
        for (int k=0;k<32;k++){ si2 += Wgi[o*36+k]*zfnv[k]; sh2 += Wgh[o*32+k]*zfv[k]; }
        #pragma unroll
        for (int k=0;k<4;k++) si2 += Wgi[o*36+32+k]*actv[k];
        giv[o]=si2; ghv[o]=sh2;
      }
    }
    __syncthreads();
    // P1b: zf update
    if (lane<32){
      float r = fsigm(giv[lane]+ghv[lane]);
      float z = fsigm(giv[32+lane]+ghv[32+lane]);
      float n = ftanh(giv[64+lane] + r*ghv[64+lane]);
      float h2 = (1.f-z)*n + z*zfv[lane];
      zfv[lane]=h2;
      out_zf[(base+t)*32+lane]=h2;
    }
    __syncthreads();
    // P2: slow-encoder hidden
    #pragma unroll
    for (int jj=0;jj<2;jj++){
      int o = lane + jj*64;
      float s = se1v[o];
      #pragma unroll 8
      for (int k=0;k<32;k++) s += Wse[o*32+k]*zfv[k];
      hidv[o] = fgelu(s);
    }
    __syncthreads();
    // P3: sp (half-split dot over 128)
    {
      int o = lane & 31, hv = lane>>5;
      float s = 0.f;
      #pragma unroll 8
      for (int k=0;k<64;k++) s += Wsp[o*128 + hv*64 + k]*hidv[hv*64+k];
      s += __shfl_xor(s,32);
      if (lane<32) spv[lane] = s + bsp[lane];
    }
    __syncthreads();
    if (lane<16) zsnv[lane] = spv[lane] + __expf(0.5f*spv[16+lane])*nsv[lane];
    __syncthreads();
    // P4: slow-GRU gates
    if (lane<48){
      float gi = bsg[lane], gh = bsh[lane];
      #pragma unroll 8
      for (int k=0;k<16;k++){ gi += Wsg[lane*48+k]*zsnv[k]; gh += Wsh[lane*16+k]*zsv[k]; }
      #pragma unroll 8
      for (int k=0;k<32;k++) gi += Wsg[lane*48+16+k]*zfv[k];
      sgiv[lane]=gi; sghv[lane]=gh;
    }
    __syncthreads();
    // P4b: zs update + blend
    if (lane<16){
      float r = fsigm(sgiv[lane]+sghv[lane]);
      float z = fsigm(sgiv[16+lane]+sghv[16+lane]);
      float n = ftanh(sgiv[32+lane]+r*sghv[32+lane]);
      float zt = (1.f-z)*n + z*zsv[lane];
      float zn = upd*zt + (1.f-upd)*zsv[lane];
      zsv[lane]=zn;
      out_zs[(base+t)*16+lane]=zn;
    }
    __syncthreads();
  }
}

// ---------------- K3: decoder, PURE VALU, fp32 in/out ----------------
__global__ __launch_bounds__(256) void k_dec(
  const float* __restrict__ izf, const float* __restrict__ izs,
  const float* __restrict__ de_w1, const float* __restrict__ de_b1,
  const float* __restrict__ de_w2, const float* __restrict__ de_b2,
  float* __restrict__ preds)
{
  __shared__ float xa[16][48];
  __shared__ float hh[16][256];
  const int tid = threadIdx.x;
  const long row0 = (long)blockIdx.x * 16;

  {
    int r = tid >> 4, c2 = (tid & 15) * 2;
    xa[r][c2]   = izf[(row0+r)*32 + c2];
    xa[r][c2+1] = izf[(row0+r)*32 + c2+1];
    int c = tid & 15;
    xa[r][32+c] = izs[(row0+r)*16 + c];
  }
  __syncthreads();

  {
    const int n = tid;
    float acc[16];
    const float bv = de_b1[n];
    #pragma unroll
    for (int r=0;r<16;r++) acc[r] = bv;
    for (int k=0;k<48;k++){
      float w = de_w1[n*48 + k];
      #pragma unroll
      for (int r=0;r<16;r++) acc[r] += w*xa[r][k];
    }
    #pragma unroll
    for (int r=0;r<16;r++) hh[r][n] = fgelu(acc[r]);
  }
  __syncthreads();

  {
    const int n = tid;
    float acc[16];
    const float bv = de_b2[n];
    #pragma unroll
    for (int r=0;r<16;r++) acc[r] = bv;
    for (int k=0;k<256;k+=4){
      f32x4 w = *(const f32x4*)(de_w2 + n*256 + k);
      #pragma unroll
      for (int j=0;j<4;j++){
        #pragma unroll
        for (int r=0;r<16;r++) acc[r] += w[j]*hh[r][k+j];
      }
    }
    #pragma unroll
    for (int r=0;r<16;r++) preds[(row0+r)*256 + n] = acc[r];
  }
}

extern "C" void kernel_launch(void* const* d_in, const int* in_sizes, int n_in,
                              void* d_out, int out_size, void* d_ws, size_t ws_size,
                              hipStream_t stream)
{
  if (n_in < 25 || in_sizes[0] != (int)(Rn*256) || in_sizes[8] != 96*36 ||
      in_sizes[12] != 128*288 || in_sizes[20] != 256*48 || in_sizes[24] != 1)
    return;
  if (out_size != (int)(Rn*304))
    return;

  const float* states = (const float*)d_in[0];
  const float* actions= (const float*)d_in[1];
  const float* nfast  = (const float*)d_in[2];
  const float* nslow  = (const float*)d_in[3];
  const float* fe_w1  = (const float*)d_in[4];
  const float* fe_b1  = (const float*)d_in[5];
  const float* fe_w2  = (const float*)d_in[6];
  const float* fe_b2  = (const float*)d_in[7];
  const float* fg_wih = (const float*)d_in[8];
  const float* fg_whh = (const float*)d_in[9];
  const float* fg_bih = (const float*)d_in[10];
  const float* fg_bhh = (const float*)d_in[11];
  const float* se_w1  = (const float*)d_in[12];
  const float* se_b1  = (const float*)d_in[13];
  const float* se_w2  = (const float*)d_in[14];
  const float* se_b2  = (const float*)d_in[15];
  const float* sg_wih = (const float*)d_in[16];
  const float* sg_whh = (const float*)d_in[17];
  const float* sg_bih = (const float*)d_in[18];
  const float* sg_bhh = (const float*)d_in[19];
  const float* de_w1  = (const float*)d_in[20];
  const float* de_b1  = (const float*)d_in[21];
  const float* de_w2  = (const float*)d_in[22];
  const float* de_b2  = (const float*)d_in[23];
  const float* updp   = (const float*)d_in[24];

  // d_out is FP32 (reference output dtype is float32): [preds | zf | zs] flat.
  float* preds = (float*)d_out;
  float* ozf = preds + Rn*256;
  float* ozs = ozf + Rn*32;

  size_t need = (size_t)Rn*32*4 + (size_t)Rn*128*2;
  float* ws_zfn; u16t* ws_se1;
  if (ws_size >= need){
    ws_zfn = (float*)d_ws;
    ws_se1 = (u16t*)((char*)d_ws + (size_t)Rn*32*4);
  } else {
    // Alias scratch inside the preds region (fp32): zfn uses floats [0, Rn*32),
    // se1 (bf16 u16) uses floats [Rn*32, Rn*96). k_dec fully overwrites preds after.
    ws_zfn = preds;
    ws_se1 = (u16t*)(preds + Rn*32);
  }

  k_pre<<<(int)(Rn/16), 256, 0, stream>>>(states, nfast,
      fe_w1, fe_b1, fe_w2, fe_b2, se_w1, se_b1, ws_zfn, ws_se1);
  k_rec<<<Bn, 64, 0, stream>>>(ws_zfn, ws_se1, actions, nslow,
      fg_wih, fg_whh, fg_bih, fg_bhh, se_w1, se_w2, se_b2,
      sg_wih, sg_whh, sg_bih, sg_bhh, updp, ozf, ozs);
  k_dec<<<(int)(Rn/16), 256, 0, stream>>>(ozf, ozs, de_w1, de_b1, de_w2, de_b2, preds);
}

// Round 11
// 2312.462 us; speedup vs baseline: 1.5516x; 1.5516x over previous
//
#include <hip/hip_runtime.h>

typedef unsigned short u16t;
typedef __attribute__((ext_vector_type(8))) short bf16x8;
typedef __attribute__((ext_vector_type(4))) float f32x4;

#define DI static __device__ __forceinline__

constexpr int Bn = 256, Tn = 512;
constexpr long Rn = (long)Bn * Tn;   // 131072 rows = (b,t) pairs

DI float b2f(u16t u){ union{unsigned u32; float f;} v; v.u32 = ((unsigned)u)<<16; return v.f; }
DI u16t f2b(float f){ union{float fp; unsigned u;} v; v.fp=f; return (u16t)((v.u + 0x7fffu + ((v.u>>16)&1u))>>16); }
DI float fsigm(float x){ return __builtin_amdgcn_rcpf(1.f + __expf(-x)); }
DI float ftanh(float x){ float e = __expf(2.f*x); return 1.f - 2.f*__builtin_amdgcn_rcpf(e+1.f); }
DI float fgelu(float x){
  float t = 0.7978845608028654f*x*(1.f + 0.044715f*x*x);
  return x*(1.f - __builtin_amdgcn_rcpf(__expf(2.f*t)+1.f));
}
DI f32x4 mfma16(bf16x8 a, bf16x8 b, f32x4 c){ return __builtin_amdgcn_mfma_f32_16x16x32_bf16(a,b,c,0,0,0); }
DI bf16x8 ldw8(const float* p){
  f32x4 a = *(const f32x4*)p, b = *(const f32x4*)(p+4);
  bf16x8 o;
  o[0]=(short)f2b(a[0]); o[1]=(short)f2b(a[1]); o[2]=(short)f2b(a[2]); o[3]=(short)f2b(a[3]);
  o[4]=(short)f2b(b[0]); o[5]=(short)f2b(b[1]); o[6]=(short)f2b(b[2]); o[7]=(short)f2b(b[3]);
  return o;
}
DI bf16x8 zero8(){ bf16x8 v; v[0]=0;v[1]=0;v[2]=0;v[3]=0;v[4]=0;v[5]=0;v[6]=0;v[7]=0; return v; }

// ---------------- K1: MFMA pre-pass, 64 rows/block ----------------
// zfn (bf16) = f_mean + exp(.5 f_lv)*nf ; se1s (bf16) = state @ se_w1[:, :256]^T + se_b1
__global__ __launch_bounds__(256) void k_pre(
    const float* __restrict__ states, const float* __restrict__ nfast,
    const float* __restrict__ fe_w1, const float* __restrict__ fe_b1,
    const float* __restrict__ fe_w2, const float* __restrict__ fe_b2,
    const float* __restrict__ se_w1, const float* __restrict__ se_b1,
    u16t* __restrict__ ws_zfn, u16t* __restrict__ ws_se1)
{
  __shared__ __align__(16) u16t s_x[64*256];   // states tile (bf16, swizzled)
  __shared__ __align__(16) u16t s_h[64*256];   // gelu(FE1) tile
  const int tid = threadIdx.x;
  const int lane = tid & 63, wave = tid >> 6;
  const int l15 = lane & 15, lh = lane >> 4;
  const long row0 = (long)blockIdx.x * 64;

  #pragma unroll
  for (int i=0;i<8;i++){
    int c = tid + i*256;
    int row = c >> 5, col = (c & 31) << 3;
    bf16x8 v = ldw8(states + (row0+row)*256 + col);
    *(bf16x8*)&s_x[row*256 + (col ^ ((row&7)<<3))] = v;
  }
  __syncthreads();

  const int wrow = wave*16;
  const int arow = wrow + l15;
  f32x4 acc1[16], acc3[8];
  #pragma unroll
  for (int nt=0;nt<16;nt++){ float bv = fe_b1[nt*16+l15]; acc1[nt] = (f32x4){bv,bv,bv,bv}; }
  #pragma unroll
  for (int nt=0;nt<8;nt++){ float bv = se_b1[nt*16+l15]; acc3[nt] = (f32x4){bv,bv,bv,bv}; }
  #pragma unroll
  for (int kt=0;kt<8;kt++){
    int acol = kt*32 + lh*8;
    bf16x8 af = *(const bf16x8*)&s_x[arow*256 + (acol ^ ((arow&7)<<3))];
    #pragma unroll
    for (int nt=0;nt<16;nt++){
      bf16x8 bw = ldw8(fe_w1 + (nt*16+l15)*256 + acol);
      acc1[nt] = mfma16(af, bw, acc1[nt]);
    }
    #pragma unroll
    for (int nt=0;nt<8;nt++){
      bf16x8 bw = ldw8(se_w1 + (nt*16+l15)*288 + acol);
      acc3[nt] = mfma16(af, bw, acc3[nt]);
    }
  }
  #pragma unroll
  for (int nt=0;nt<8;nt++){
    #pragma unroll
    for (int r=0;r<4;r++){
      int row = wrow + lh*4 + r;
      ws_se1[(row0+row)*128 + nt*16+l15] = f2b(acc3[nt][r]);
    }
  }
  #pragma unroll
  for (int nt=0;nt<16;nt++){
    #pragma unroll
    for (int r=0;r<4;r++){
      int row = wrow + lh*4 + r; int col = nt*16 + l15;
      s_h[row*256 + (col ^ ((row&7)<<3))] = f2b(fgelu(acc1[nt][r]));
    }
  }
  __syncthreads();
  f32x4 acc2[4];
  #pragma unroll
  for (int a=0;a<4;a++){ float bv = fe_b2[a*16+l15]; acc2[a] = (f32x4){bv,bv,bv,bv}; }
  #pragma unroll
  for (int kt=0;kt<8;kt++){
    int acol = kt*32 + lh*8;
    bf16x8 af = *(const bf16x8*)&s_h[arow*256 + (acol ^ ((arow&7)<<3))];
    #pragma unroll
    for (int a=0;a<4;a++){
      bf16x8 bw = ldw8(fe_w2 + (a*16+l15)*256 + acol);
      acc2[a] = mfma16(af, bw, acc2[a]);
    }
  }
  #pragma unroll
  for (int a=0;a<2;a++){
    #pragma unroll
    for (int r=0;r<4;r++){
      int row = wrow + lh*4 + r; int col = a*16 + l15;
      float nfv = nfast[(row0+row)*32 + col];
      float zv = acc2[a][r] + __expf(0.5f*acc2[a+2][r])*nfv;
      ws_zfn[(row0+row)*32 + col] = f2b(zv);
    }
  }
}

// ---------------- K2: MFMA recurrence, 16 blocks x 1 wave x 16 batch rows ----------------
// Plain row-major LDS, __syncthreads between phases (R5 structure, fp32 outputs).
__global__ __launch_bounds__(64,1) void k_rec(
  const u16t* __restrict__ ws_zfn, const u16t* __restrict__ ws_se1,
  const float* __restrict__ actions, const float* __restrict__ noise_slow,
  const float* __restrict__ fg_wih, const float* __restrict__ fg_whh,
  const float* __restrict__ fg_bih, const float* __restrict__ fg_bhh,
  const float* __restrict__ se_w1, const float* __restrict__ se_w2, const float* __restrict__ se_b2,
  const float* __restrict__ sg_wih, const float* __restrict__ sg_whh,
  const float* __restrict__ sg_bih, const float* __restrict__ sg_bhh,
  const float* __restrict__ updp,
  float* __restrict__ out_zf, float* __restrict__ out_zs)
{
  __shared__ __align__(16) u16t  zfa [16*64];   // [row][0:32)=zfn, [32:36)=act, rest 0
  __shared__ __align__(16) u16t  hzf [16*64];   // [row][0:16)=zsn, [16:48)=zf, rest 0
  __shared__ __align__(16) u16t  se1b[16*128];
  __shared__ __align__(16) float nsb [16*16];
  __shared__ __align__(16) u16t  hidb[16*128];
  __shared__ __align__(16) u16t  zsb2[16*32];   // [row][0:16)=zs, rest 0
  const int lane = threadIdx.x;
  const int l15 = lane & 15, lh = lane >> 4;
  const long b0 = (long)blockIdx.x * 16;

  // ---- weight B-fragments in registers (static for whole kernel) ----
  bf16x8 Fwih[6][2], Fwhh[6], Fsw1[8], Fsw2[2][4], Fsgi[3][2], Fsgh[3];
  #pragma unroll
  for (int nt=0;nt<6;nt++){
    Fwih[nt][0] = ldw8(fg_wih + (nt*16+l15)*36 + lh*8);
    bf16x8 v = zero8();
    if (lh==0){
      #pragma unroll
      for (int e=0;e<4;e++) v[e] = (short)f2b(fg_wih[(nt*16+l15)*36 + 32 + e]);
    }
    Fwih[nt][1] = v;
    Fwhh[nt] = ldw8(fg_whh + (nt*16+l15)*32 + lh*8);
  }
  #pragma unroll
  for (int nt=0;nt<8;nt++) Fsw1[nt] = ldw8(se_w1 + (nt*16+l15)*288 + 256 + lh*8);
  #pragma unroll
  for (int nt=0;nt<2;nt++){
    #pragma unroll
    for (int kt=0;kt<4;kt++) Fsw2[nt][kt] = ldw8(se_w2 + (nt*16+l15)*128 + kt*32 + lh*8);
  }
  #pragma unroll
  for (int nt=0;nt<3;nt++){
    #pragma unroll
    for (int kt=0;kt<2;kt++){
      bf16x8 v = zero8();
      if (!(kt==1 && lh>=2)) v = ldw8(sg_wih + (nt*16+l15)*48 + kt*32 + lh*8);
      Fsgi[nt][kt] = v;
    }
    {
      bf16x8 v = zero8();
      if (lh < 2) v = ldw8(sg_whh + (nt*16+l15)*16 + lh*8);
      Fsgh[nt] = v;
    }
  }
  float bih_c[6], bhh_c[6], seb2_c[2], sgbi_c[3], sgbh_c[3];
  #pragma unroll
  for (int nt=0;nt<6;nt++){ bih_c[nt] = fg_bih[nt*16+l15]; bhh_c[nt] = fg_bhh[nt*16+l15]; }
  #pragma unroll
  for (int nt=0;nt<2;nt++) seb2_c[nt] = se_b2[nt*16+l15];
  #pragma unroll
  for (int nt=0;nt<3;nt++){ sgbi_c[nt]=sg_bih[nt*16+l15]; sgbh_c[nt]=sg_bhh[nt*16+l15]; }
  const float upd = fsigm(updp[0]);

  // zero-init LDS state/pad (done once; pad regions never rewritten)
  for (int e=0;e<16;e++){ zfa[lane*16+e]=0; hzf[lane*16+e]=0; }
  for (int e=0;e<8;e++) zsb2[lane*8+e]=0;
  float zf_r[2][4] = {{0,0,0,0},{0,0,0,0}};
  float zs_r[4] = {0,0,0,0};

  bf16x8 pf_zfn, pf_se[4]; float pf_act; f32x4 pf_ns;
  const int prow = lane >> 2, pq = lane & 3;
  auto pfload = [&](int tt){
    pf_zfn = *(const bf16x8*)(ws_zfn + ((b0+prow)*Tn + tt)*32 + pq*8);
    #pragma unroll
    for (int i=0;i<4;i++){ int c = i*64+lane; int row = c>>4; int off=(c&15)*8;
      pf_se[i] = *(const bf16x8*)(ws_se1 + ((b0+row)*Tn + tt)*128 + off); }
    pf_act = actions[((b0+prow)*Tn + tt)*4 + pq];
    pf_ns  = *(const f32x4*)(noise_slow + ((b0+prow)*Tn + tt)*16 + pq*4);
  };
  pfload(0);

  for (int t=0; t<Tn; t++){
    // commit prefetched step-t data to LDS
    *(bf16x8*)&zfa[prow*64 + pq*8] = pf_zfn;
    zfa[prow*64 + 32 + pq] = f2b(pf_act);
    #pragma unroll
    for (int i=0;i<4;i++) *(bf16x8*)&se1b[(i*64+lane)*8] = pf_se[i];
    *(f32x4*)&nsb[prow*16 + pq*4] = pf_ns;
    __syncthreads();
    if (t+1 < Tn) pfload(t+1);

    // ---- fast GRU: gi = [zfn,act]@wih^T + bih ; gh = zf_prev@whh^T + bhh ----
    {
      f32x4 gi[6], gh[6];
      #pragma unroll
      for (int nt=0;nt<6;nt++){ float bi=bih_c[nt], bh=bhh_c[nt];
        gi[nt]=(f32x4){bi,bi,bi,bi}; gh[nt]=(f32x4){bh,bh,bh,bh}; }
      #pragma unroll
      for (int kt=0;kt<2;kt++){
        bf16x8 ax = *(const bf16x8*)&zfa[l15*64 + kt*32 + lh*8];
        #pragma unroll
        for (int nt=0;nt<6;nt++) gi[nt] = mfma16(ax, Fwih[nt][kt], gi[nt]);
      }
      {
        bf16x8 az = *(const bf16x8*)&hzf[l15*64 + 16 + lh*8];
        #pragma unroll
        for (int nt=0;nt<6;nt++) gh[nt] = mfma16(az, Fwhh[nt], gh[nt]);
      }
      #pragma unroll
      for (int a=0;a<2;a++){
        #pragma unroll
        for (int r=0;r<4;r++){
          int row = lh*4+r; int cg = a*16+l15;
          float rg = fsigm(gi[a][r]   + gh[a][r]);
          float zg = fsigm(gi[2+a][r] + gh[2+a][r]);
          float ng = ftanh(gi[4+a][r] + rg*gh[4+a][r]);
          float hv = (1.f-zg)*ng + zg*zf_r[a][r];
          zf_r[a][r] = hv;
          hzf[row*64 + 16 + cg] = f2b(hv);
          out_zf[((b0+row)*Tn + t)*32 + cg] = hv;
        }
      }
    }
    __syncthreads();
    // ---- slow encoder: hid = gelu(se1s + zf_new @ Wzf^T) ----
    {
      bf16x8 azf2 = *(const bf16x8*)&hzf[l15*64 + 16 + lh*8];
      f32x4 se[8];
      #pragma unroll
      for (int nt=0;nt<8;nt++){
        f32x4 c;
        #pragma unroll
        for (int r=0;r<4;r++) c[r] = b2f(se1b[(lh*4+r)*128 + nt*16+l15]);
        se[nt] = mfma16(azf2, Fsw1[nt], c);
      }
      #pragma unroll
      for (int nt=0;nt<8;nt++){
        #pragma unroll
        for (int r=0;r<4;r++)
          hidb[(lh*4+r)*128 + nt*16+l15] = f2b(fgelu(se[nt][r]));
      }
    }
    __syncthreads();
    // ---- sp = hid @ se_w2^T + b2 ; reparam slow -> zsn ----
    {
      f32x4 sp[2];
      #pragma unroll
      for (int nt=0;nt<2;nt++){ float bv=seb2_c[nt]; sp[nt]=(f32x4){bv,bv,bv,bv}; }
      #pragma unroll
      for (int kt=0;kt<4;kt++){
        bf16x8 ah = *(const bf16x8*)&hidb[l15*128 + kt*32 + lh*8];
        #pragma unroll
        for (int nt=0;nt<2;nt++) sp[nt] = mfma16(ah, Fsw2[nt][kt], sp[nt]);
      }
      #pragma unroll
      for (int r=0;r<4;r++){
        int row = lh*4+r;
        float nsv = nsb[row*16 + l15];
        float zn = sp[0][r] + __expf(0.5f*sp[1][r])*nsv;
        hzf[row*64 + l15] = f2b(zn);
      }
    }
    __syncthreads();
    // ---- slow GRU + blend ----
    {
      f32x4 gi2[3], gh2[3];
      #pragma unroll
      for (int nt=0;nt<3;nt++){ float bi=sgbi_c[nt], bh=sgbh_c[nt];
        gi2[nt]=(f32x4){bi,bi,bi,bi}; gh2[nt]=(f32x4){bh,bh,bh,bh}; }
      {
        bf16x8 azs = *(const bf16x8*)&zsb2[l15*32 + lh*8];
        #pragma unroll
        for (int nt=0;nt<3;nt++) gh2[nt] = mfma16(azs, Fsgh[nt], gh2[nt]);
      }
      #pragma unroll
      for (int kt=0;kt<2;kt++){
        bf16x8 ax = *(const bf16x8*)&hzf[l15*64 + kt*32 + lh*8];
        #pragma unroll
        for (int nt=0;nt<3;nt++) gi2[nt] = mfma16(ax, Fsgi[nt][kt], gi2[nt]);
      }
      #pragma unroll
      for (int r=0;r<4;r++){
        int row = lh*4+r;
        float rg = fsigm(gi2[0][r] + gh2[0][r]);
        float zg = fsigm(gi2[1][r] + gh2[1][r]);
        float ng = ftanh(gi2[2][r] + rg*gh2[2][r]);
        float zt = (1.f-zg)*ng + zg*zs_r[r];
        float zn = upd*zt + (1.f-upd)*zs_r[r];
        zs_r[r] = zn;
        zsb2[row*32 + l15] = f2b(zn);
        out_zs[((b0+row)*Tn + t)*16 + l15] = zn;
      }
    }
    __syncthreads();
  }
}

// ---------------- K3: MFMA decoder, 64 rows/block, fp32 in/out ----------------
__global__ __launch_bounds__(256) void k_dec(
  const float* __restrict__ izf, const float* __restrict__ izs,
  const float* __restrict__ de_w1, const float* __restrict__ de_b1,
  const float* __restrict__ de_w2, const float* __restrict__ de_b2,
  float* __restrict__ preds)
{
  __shared__ __align__(16) u16t s_a[64*64];
  __shared__ __align__(16) u16t s_h[64*256];
  const int tid = threadIdx.x;
  const int lane = tid & 63, wave = tid >> 6;
  const int l15 = lane & 15, lh = lane >> 4;
  const long row0 = (long)blockIdx.x * 64;

  { int row = tid >> 2, col = (tid & 3) << 3;
    bf16x8 v = ldw8(izf + (row0+row)*32 + col);
    *(bf16x8*)&s_a[row*64 + (col ^ ((row&7)<<3))] = v; }
  if (tid < 128){
    int row = tid >> 1, col = 32 + ((tid & 1) << 3);
    bf16x8 v = ldw8(izs + (row0+row)*16 + ((tid&1)<<3));
    *(bf16x8*)&s_a[row*64 + (col ^ ((row&7)<<3))] = v;
  } else {
    int t2 = tid - 128;
    int row = t2 >> 1, col = 48 + ((t2 & 1) << 3);
    bf16x8 v = zero8();
    *(bf16x8*)&s_a[row*64 + (col ^ ((row&7)<<3))] = v;
  }
  __syncthreads();

  const int wrow = wave*16;
  const int arow = wrow + l15;
  f32x4 acc[16];
  #pragma unroll
  for (int nt=0;nt<16;nt++){ float bv = de_b1[nt*16+l15]; acc[nt] = (f32x4){bv,bv,bv,bv}; }
  #pragma unroll
  for (int kt=0;kt<2;kt++){
    int acol = kt*32 + lh*8;
    bf16x8 af = *(const bf16x8*)&s_a[arow*64 + (acol ^ ((arow&7)<<3))];
    #pragma unroll
    for (int nt=0;nt<16;nt++){
      bf16x8 bw = zero8();
      if (!(kt==1 && lh>=2)) bw = ldw8(de_w1 + (nt*16+l15)*48 + acol);
      acc[nt] = mfma16(af, bw, acc[nt]);
    }
  }
  #pragma unroll
  for (int nt=0;nt<16;nt++){
    #pragma unroll
    for (int r=0;r<4;r++){
      int row = wrow + lh*4 + r; int col = nt*16 + l15;
      s_h[row*256 + (col ^ ((row&7)<<3))] = f2b(fgelu(acc[nt][r]));
    }
  }
  __syncthreads();
  f32x4 a2[16];
  #pragma unroll
  for (int nt=0;nt<16;nt++){ float bv = de_b2[nt*16+l15]; a2[nt] = (f32x4){bv,bv,bv,bv}; }
  #pragma unroll
  for (int kt=0;kt<8;kt++){
    int acol = kt*32 + lh*8;
    bf16x8 af = *(const bf16x8*)&s_h[arow*256 + (acol ^ ((arow&7)<<3))];
    #pragma unroll
    for (int nt=0;nt<16;nt++){
      bf16x8 bw = ldw8(de_w2 + (nt*16+l15)*256 + acol);
      a2[nt] = mfma16(af, bw, a2[nt]);
    }
  }
  #pragma unroll
  for (int nt=0;nt<16;nt++){
    #pragma unroll
    for (int r=0;r<4;r++){
      int row = wrow + lh*4 + r;
      preds[(row0+row)*256 + nt*16+l15] = a2[nt][r];
    }
  }
}

extern "C" void kernel_launch(void* const* d_in, const int* in_sizes, int n_in,
                              void* d_out, int out_size, void* d_ws, size_t ws_size,
                              hipStream_t stream)
{
  if (n_in < 25 || in_sizes[0] != (int)(Rn*256) || in_sizes[8] != 96*36 ||
      in_sizes[12] != 128*288 || in_sizes[20] != 256*48 || in_sizes[24] != 1)
    return;
  if (out_size != (int)(Rn*304))
    return;

  const float* states = (const float*)d_in[0];
  const float* actions= (const float*)d_in[1];
  const float* nfast  = (const float*)d_in[2];
  const float* nslow  = (const float*)d_in[3];
  const float* fe_w1  = (const float*)d_in[4];
  const float* fe_b1  = (const float*)d_in[5];
  const float* fe_w2  = (const float*)d_in[6];
  const float* fe_b2  = (const float*)d_in[7];
  const float* fg_wih = (const float*)d_in[8];
  const float* fg_whh = (const float*)d_in[9];
  const float* fg_bih = (const float*)d_in[10];
  const float* fg_bhh = (const float*)d_in[11];
  const float* se_w1  = (const float*)d_in[12];
  const float* se_b1  = (const float*)d_in[13];
  const float* se_w2  = (const float*)d_in[14];
  const float* se_b2  = (const float*)d_in[15];
  const float* sg_wih = (const float*)d_in[16];
  const float* sg_whh = (const float*)d_in[17];
  const float* sg_bih = (const float*)d_in[18];
  const float* sg_bhh = (const float*)d_in[19];
  const float* de_w1  = (const float*)d_in[20];
  const float* de_b1  = (const float*)d_in[21];
  const float* de_w2  = (const float*)d_in[22];
  const float* de_b2  = (const float*)d_in[23];
  const float* updp   = (const float*)d_in[24];

  // d_out is FP32: [preds | zf | zs] flat.
  float* preds = (float*)d_out;
  float* ozf = preds + Rn*256;
  float* ozs = ozf + Rn*32;

  // Scratch: zfn bf16 [Rn][32] + se1 bf16 [Rn][128] = Rn*320 bytes.
  size_t need = (size_t)Rn*320;
  u16t* ws_zfn; u16t* ws_se1;
  if (ws_size >= need){
    ws_zfn = (u16t*)d_ws;
    ws_se1 = ws_zfn + Rn*32;
  } else {
    // Alias inside preds fp32 region (Rn*1024 bytes >= Rn*320); k_dec overwrites after.
    ws_zfn = (u16t*)preds;
    ws_se1 = ws_zfn + Rn*32;
  }

  k_pre<<<(int)(Rn/64), 256, 0, stream>>>(states, nfast,
      fe_w1, fe_b1, fe_w2, fe_b2, se_w1, se_b1, ws_zfn, ws_se1);
  k_rec<<<Bn/16, 64, 0, stream>>>(ws_zfn, ws_se1, actions, nslow,
      fg_wih, fg_whh, fg_bih, fg_bhh, se_w1, se_w2, se_b2,
      sg_wih, sg_whh, sg_bih, sg_bhh, updp, ozf, ozs);
  k_dec<<<(int)(Rn/64), 256, 0, stream>>>(ozf, ozs, de_w1, de_b1, de_w2, de_b2, preds);
}

// Round 12
// 2002.679 us; speedup vs baseline: 1.7916x; 1.1547x over previous
//
#include <hip/hip_runtime.h>

typedef unsigned short u16t;
typedef __attribute__((ext_vector_type(8))) short bf16x8;
typedef __attribute__((ext_vector_type(4))) float f32x4;

#define DI static __device__ __forceinline__

constexpr int Bn = 256, Tn = 512;
constexpr long Rn = (long)Bn * Tn;   // 131072 rows = (b,t) pairs

DI float b2f(u16t u){ union{unsigned u32; float f;} v; v.u32 = ((unsigned)u)<<16; return v.f; }
DI u16t f2b(float f){ union{float fp; unsigned u;} v; v.fp=f; return (u16t)((v.u + 0x7fffu + ((v.u>>16)&1u))>>16); }
DI float fsigm(float x){ return __builtin_amdgcn_rcpf(1.f + __expf(-x)); }
DI float ftanh(float x){ float e = __expf(2.f*x); return 1.f - 2.f*__builtin_amdgcn_rcpf(e+1.f); }
DI float fgelu(float x){
  float t = 0.7978845608028654f*x*(1.f + 0.044715f*x*x);
  return x*(1.f - __builtin_amdgcn_rcpf(__expf(2.f*t)+1.f));
}
DI f32x4 mfma16(bf16x8 a, bf16x8 b, f32x4 c){ return __builtin_amdgcn_mfma_f32_16x16x32_bf16(a,b,c,0,0,0); }
// truncation pack: two fp32 -> one u32 of 2 bf16 (forward-only data / weights)
DI unsigned pk2(float a, float b){
  union{float f; unsigned u;} x, y; x.f=a; y.f=b;
  return (x.u>>16) | (y.u & 0xffff0000u);
}
// RNE pack (recurrent-state data)
DI unsigned pkr(float a, float b){ return (unsigned)f2b(a) | ((unsigned)f2b(b)<<16); }
DI bf16x8 mk8(unsigned w0,unsigned w1,unsigned w2,unsigned w3){
  union{unsigned u[4]; bf16x8 v;} z; z.u[0]=w0; z.u[1]=w1; z.u[2]=w2; z.u[3]=w3; return z.v;
}
DI unsigned bperm(int srcLane, unsigned v){
  return (unsigned)__builtin_amdgcn_ds_bpermute(srcLane<<2, (int)v);
}
// load 8 consecutive fp32 -> bf16x8 (truncation; inputs are fp32 on device)
DI bf16x8 ldw8(const float* p){
  f32x4 a = *(const f32x4*)p, b = *(const f32x4*)(p+4);
  return mk8(pk2(a[0],a[1]), pk2(a[2],a[3]), pk2(b[0],b[1]), pk2(b[2],b[3]));
}
DI bf16x8 zero8(){ bf16x8 v; v[0]=0;v[1]=0;v[2]=0;v[3]=0;v[4]=0;v[5]=0;v[6]=0;v[7]=0; return v; }

// ---------------- K1: MFMA pre-pass, 64 rows/block ----------------
// zfn (bf16, [row][32]) ; se1s (bf16, PERMUTED: [row][ (l15>>2)*32 + nt*4 + (l15&3) ])
__global__ __launch_bounds__(256) void k_pre(
    const float* __restrict__ states, const float* __restrict__ nfast,
    const float* __restrict__ fe_w1, const float* __restrict__ fe_b1,
    const float* __restrict__ fe_w2, const float* __restrict__ fe_b2,
    const float* __restrict__ se_w1, const float* __restrict__ se_b1,
    u16t* __restrict__ ws_zfn, u16t* __restrict__ ws_se1)
{
  __shared__ __align__(16) u16t s_x[64*256];
  __shared__ __align__(16) u16t s_h[64*256];
  const int tid = threadIdx.x;
  const int lane = tid & 63, wave = tid >> 6;
  const int l15 = lane & 15, lh = lane >> 4;
  const long row0 = (long)blockIdx.x * 64;

  #pragma unroll
  for (int i=0;i<8;i++){
    int c = tid + i*256;
    int row = c >> 5, col = (c & 31) << 3;
    bf16x8 v = ldw8(states + (row0+row)*256 + col);
    *(bf16x8*)&s_x[row*256 + (col ^ ((row&7)<<3))] = v;
  }
  __syncthreads();

  const int wrow = wave*16;
  const int arow = wrow + l15;
  f32x4 acc1[16], acc3[8];
  #pragma unroll
  for (int nt=0;nt<16;nt++){ float bv = fe_b1[nt*16+l15]; acc1[nt] = (f32x4){bv,bv,bv,bv}; }
  #pragma unroll
  for (int nt=0;nt<8;nt++){ float bv = se_b1[nt*16+l15]; acc3[nt] = (f32x4){bv,bv,bv,bv}; }
  #pragma unroll
  for (int kt=0;kt<8;kt++){
    int acol = kt*32 + lh*8;
    bf16x8 af = *(const bf16x8*)&s_x[arow*256 + (acol ^ ((arow&7)<<3))];
    #pragma unroll
    for (int nt=0;nt<16;nt++){
      bf16x8 bw = ldw8(fe_w1 + (nt*16+l15)*256 + acol);
      acc1[nt] = mfma16(af, bw, acc1[nt]);
    }
    #pragma unroll
    for (int nt=0;nt<8;nt++){
      bf16x8 bw = ldw8(se_w1 + (nt*16+l15)*288 + acol);
      acc3[nt] = mfma16(af, bw, acc3[nt]);
    }
  }
  // store se1s in k_rec's permuted per-lane layout
  #pragma unroll
  for (int nt=0;nt<8;nt++){
    #pragma unroll
    for (int r=0;r<4;r++){
      int row = wrow + lh*4 + r;
      ws_se1[(row0+row)*128 + (l15>>2)*32 + nt*4 + (l15&3)] = f2b(acc3[nt][r]);
    }
  }
  #pragma unroll
  for (int nt=0;nt<16;nt++){
    #pragma unroll
    for (int r=0;r<4;r++){
      int row = wrow + lh*4 + r; int col = nt*16 + l15;
      s_h[row*256 + (col ^ ((row&7)<<3))] = f2b(fgelu(acc1[nt][r]));
    }
  }
  __syncthreads();
  f32x4 acc2[4];
  #pragma unroll
  for (int a=0;a<4;a++){ float bv = fe_b2[a*16+l15]; acc2[a] = (f32x4){bv,bv,bv,bv}; }
  #pragma unroll
  for (int kt=0;kt<8;kt++){
    int acol = kt*32 + lh*8;
    bf16x8 af = *(const bf16x8*)&s_h[arow*256 + (acol ^ ((arow&7)<<3))];
    #pragma unroll
    for (int a=0;a<4;a++){
      bf16x8 bw = ldw8(fe_w2 + (a*16+l15)*256 + acol);
      acc2[a] = mfma16(af, bw, acc2[a]);
    }
  }
  #pragma unroll
  for (int a=0;a<2;a++){
    #pragma unroll
    for (int r=0;r<4;r++){
      int row = wrow + lh*4 + r; int col = a*16 + l15;
      float nfv = nfast[(row0+row)*32 + col];
      float zv = acc2[a][r] + __expf(0.5f*acc2[a+2][r])*nfv;
      ws_zfn[(row0+row)*32 + col] = f2b(zv);
    }
  }
}

// ---------------- K2: swapped-operand MFMA recurrence — NO LDS, NO BARRIERS ----------------
// 16 blocks x 1 wave; lane owns batch row l15; D = W·X^T keeps batch on l15 everywhere.
// Cross-phase fragment transposes via ds_bpermute within 4-lane groups {l15,+16,+32,+48}.
__global__ __launch_bounds__(64,1) void k_rec(
  const u16t* __restrict__ ws_zfn, const u16t* __restrict__ ws_se1,
  const float* __restrict__ actions, const float* __restrict__ noise_slow,
  const float* __restrict__ fg_wih, const float* __restrict__ fg_whh,
  const float* __restrict__ fg_bih, const float* __restrict__ fg_bhh,
  const float* __restrict__ se_w1, const float* __restrict__ se_w2, const float* __restrict__ se_b2,
  const float* __restrict__ sg_wih, const float* __restrict__ sg_whh,
  const float* __restrict__ sg_bih, const float* __restrict__ sg_bhh,
  const float* __restrict__ updp,
  float* __restrict__ out_zf, float* __restrict__ out_zs)
{
  const int lane = threadIdx.x;
  const int l15 = lane & 15, lh = lane >> 4;
  const long b0 = (long)blockIdx.x * 16;
  const long rowT = (b0 + l15) * (long)Tn;

  // ---- A-fragments (weights): lane holds W[row = nt*16+l15][k = lh*8+e] ----
  bf16x8 Awih[6][2], Awhh[6], Awse[8], Awsp[2][4], Awsg[3][2], Awsh[3];
  #pragma unroll
  for (int nt=0;nt<6;nt++){
    Awih[nt][0] = ldw8(fg_wih + (nt*16+l15)*36 + lh*8);
    bf16x8 v = zero8();
    if (lh==0){
      #pragma unroll
      for (int e=0;e<4;e++) v[e] = (short)f2b(fg_wih[(nt*16+l15)*36 + 32 + e]);
    }
    Awih[nt][1] = v;
    Awhh[nt] = ldw8(fg_whh + (nt*16+l15)*32 + lh*8);
  }
  #pragma unroll
  for (int nt=0;nt<8;nt++) Awse[nt] = ldw8(se_w1 + (nt*16+l15)*288 + 256 + lh*8);
  #pragma unroll
  for (int nt=0;nt<2;nt++){
    #pragma unroll
    for (int kt=0;kt<4;kt++) Awsp[nt][kt] = ldw8(se_w2 + (nt*16+l15)*128 + kt*32 + lh*8);
  }
  #pragma unroll
  for (int nt=0;nt<3;nt++){
    Awsg[nt][0] = ldw8(sg_wih + (nt*16+l15)*48 + lh*8);
    bf16x8 v = zero8();
    if (lh < 2) v = ldw8(sg_wih + (nt*16+l15)*48 + 32 + lh*8);
    Awsg[nt][1] = v;
    bf16x8 w = zero8();
    if (lh < 2) w = ldw8(sg_whh + (nt*16+l15)*16 + lh*8);
    Awsh[nt] = w;
  }
  // ---- per-lane biases: D row = nt*16 + lh*4 + r ----
  float bih_l[6][4], bhh_l[6][4], bsp_l[2][4], bsg_l[3][4], bsh_l[3][4];
  #pragma unroll
  for (int nt=0;nt<6;nt++){
    #pragma unroll
    for (int r=0;r<4;r++){ bih_l[nt][r]=fg_bih[nt*16+lh*4+r]; bhh_l[nt][r]=fg_bhh[nt*16+lh*4+r]; }
  }
  #pragma unroll
  for (int nt=0;nt<2;nt++){
    #pragma unroll
    for (int r=0;r<4;r++) bsp_l[nt][r]=se_b2[nt*16+lh*4+r];
  }
  #pragma unroll
  for (int nt=0;nt<3;nt++){
    #pragma unroll
    for (int r=0;r<4;r++){ bsg_l[nt][r]=sg_bih[nt*16+lh*4+r]; bsh_l[nt][r]=sg_bhh[nt*16+lh*4+r]; }
  }
  const float upd = fsigm(updp[0]);

  // recurrent state
  unsigned zfw[4] = {0,0,0,0};   // zf B-frag words
  unsigned zsw[4] = {0,0,0,0};   // zs B-frag words (lh<2 live)
  float zf_r[2][4] = {{0,0,0,0},{0,0,0,0}};
  float zs_r[4] = {0,0,0,0};

  bf16x8 pf_zfn, pf_se[4]; f32x4 pf_act, pf_ns;
  auto pfload = [&](int tt){
    pf_zfn = *(const bf16x8*)(ws_zfn + (rowT+tt)*32 + lh*8);
    #pragma unroll
    for (int i=0;i<4;i++) pf_se[i] = *(const bf16x8*)(ws_se1 + (rowT+tt)*128 + lh*32 + i*8);
    pf_act = *(const f32x4*)(actions + (rowT+tt)*4);
    pf_ns  = *(const f32x4*)(noise_slow + (rowT+tt)*16 + lh*4);
  };
  pfload(0);

  for (int t=0; t<Tn; t++){
    bf16x8 zfnB = pf_zfn;
    bf16x8 seP0 = pf_se[0], seP1 = pf_se[1], seP2 = pf_se[2], seP3 = pf_se[3];
    f32x4 actv = pf_act, nsv = pf_ns;
    if (t+1 < Tn) pfload(t+1);

    bf16x8 actB = zero8();
    if (lh==0) actB = mk8(pk2(actv[0],actv[1]), pk2(actv[2],actv[3]), 0, 0);

    // ---- Phase F: fast GRU ----
    f32x4 gi[6], gh[6];
    #pragma unroll
    for (int nt=0;nt<6;nt++){
      gi[nt] = (f32x4){bih_l[nt][0],bih_l[nt][1],bih_l[nt][2],bih_l[nt][3]};
      gh[nt] = (f32x4){bhh_l[nt][0],bhh_l[nt][1],bhh_l[nt][2],bhh_l[nt][3]};
    }
    bf16x8 zfB = mk8(zfw[0],zfw[1],zfw[2],zfw[3]);
    #pragma unroll
    for (int nt=0;nt<6;nt++) gi[nt] = mfma16(Awih[nt][0], zfnB, gi[nt]);
    #pragma unroll
    for (int nt=0;nt<6;nt++) gi[nt] = mfma16(Awih[nt][1], actB, gi[nt]);
    #pragma unroll
    for (int nt=0;nt<6;nt++) gh[nt] = mfma16(Awhh[nt], zfB, gh[nt]);
    float hv[2][4];
    #pragma unroll
    for (int a=0;a<2;a++){
      #pragma unroll
      for (int r=0;r<4;r++){
        float rg = fsigm(gi[a][r]   + gh[a][r]);
        float zg = fsigm(gi[2+a][r] + gh[2+a][r]);
        float ng = ftanh(gi[4+a][r] + rg*gh[4+a][r]);
        float h2 = (1.f-zg)*ng + zg*zf_r[a][r];
        zf_r[a][r] = h2; hv[a][r] = h2;
      }
      f32x4 o = (f32x4){hv[a][0],hv[a][1],hv[a][2],hv[a][3]};
      *(f32x4*)(out_zf + (rowT+t)*32 + a*16 + lh*4) = o;
    }
    // T1: zf D->B (RNE packs, 8 bperm + select)
    {
      unsigned P00=pkr(hv[0][0],hv[0][1]), P01=pkr(hv[0][2],hv[0][3]);
      unsigned P10=pkr(hv[1][0],hv[1][1]), P11=pkr(hv[1][2],hv[1][3]);
      #pragma unroll
      for (int w=0;w<4;w++){
        int srcl = ((2*(lh&1) + (w>>1))<<4) + l15;
        unsigned r0 = bperm(srcl, (w&1)?P01:P00);
        unsigned r1 = bperm(srcl, (w&1)?P11:P10);
        zfw[w] = (lh>>1) ? r1 : r0;
      }
    }
    bf16x8 zfBn = mk8(zfw[0],zfw[1],zfw[2],zfw[3]);

    // ---- Phase S1: slow encoder hid = gelu(se1s + zf@Wse^T) ----
    unsigned HP[8][2];
    #pragma unroll
    for (int nt=0;nt<8;nt++){
      f32x4 c;
      #pragma unroll
      for (int r=0;r<4;r++){
        int e = (nt&1)*4 + r;
        u16t sv = (nt>>1)==0 ? (u16t)seP0[e] : (nt>>1)==1 ? (u16t)seP1[e]
                 : (nt>>1)==2 ? (u16t)seP2[e] : (u16t)seP3[e];
        c[r] = b2f(sv);
      }
      f32x4 se = mfma16(Awse[nt], zfBn, c);
      float g0=fgelu(se[0]), g1=fgelu(se[1]), g2=fgelu(se[2]), g3=fgelu(se[3]);
      HP[nt][0]=pk2(g0,g1); HP[nt][1]=pk2(g2,g3);
    }
    // T2: hid D->B (32 bperm + select)
    bf16x8 hidB[4];
    #pragma unroll
    for (int kt=0;kt<4;kt++){
      unsigned ww[4];
      #pragma unroll
      for (int w=0;w<4;w++){
        int srcl = ((2*(lh&1) + (w>>1))<<4) + l15;
        unsigned r0 = bperm(srcl, HP[2*kt  ][w&1]);
        unsigned r1 = bperm(srcl, HP[2*kt+1][w&1]);
        ww[w] = (lh>>1) ? r1 : r0;
      }
      hidB[kt] = mk8(ww[0],ww[1],ww[2],ww[3]);
    }

    // ---- Phase S2: sp = hid@Wsp^T + b2 ; slow reparam ----
    f32x4 sp[2];
    #pragma unroll
    for (int nt=0;nt<2;nt++) sp[nt] = (f32x4){bsp_l[nt][0],bsp_l[nt][1],bsp_l[nt][2],bsp_l[nt][3]};
    #pragma unroll
    for (int kt=0;kt<4;kt++){
      #pragma unroll
      for (int nt=0;nt<2;nt++) sp[nt] = mfma16(Awsp[nt][kt], hidB[kt], sp[nt]);
    }
    float zsn[4];
    #pragma unroll
    for (int r=0;r<4;r++) zsn[r] = sp[0][r] + __expf(0.5f*sp[1][r])*nsv[r];
    // T3: build slow-GRU B-frags [zsn | zf]
    bf16x8 sgB0, sgB1;
    {
      unsigned QZ0=pk2(zsn[0],zsn[1]), QZ1=pk2(zsn[2],zsn[3]);
      unsigned w0_[4], w1_[4];
      int srcF = ((lh^2)<<4) + l15;
      #pragma unroll
      for (int w=0;w<4;w++){
        int srcZ = ((2*(lh&1) + (w>>1))<<4) + l15;
        unsigned vz = bperm(srcZ, (w&1)?QZ1:QZ0);
        unsigned vf = bperm(srcF, zfw[w]);
        w0_[w] = (lh<2) ? vz : vf;
        w1_[w] = (lh<2) ? vf : 0u;
      }
      sgB0 = mk8(w0_[0],w0_[1],w0_[2],w0_[3]);
      sgB1 = mk8(w1_[0],w1_[1],w1_[2],w1_[3]);
    }

    // ---- Phase S3: slow GRU + blend ----
    f32x4 gi2[3], gh2[3];
    #pragma unroll
    for (int nt=0;nt<3;nt++){
      gi2[nt] = (f32x4){bsg_l[nt][0],bsg_l[nt][1],bsg_l[nt][2],bsg_l[nt][3]};
      gh2[nt] = (f32x4){bsh_l[nt][0],bsh_l[nt][1],bsh_l[nt][2],bsh_l[nt][3]};
    }
    bf16x8 zsB = mk8(zsw[0],zsw[1],zsw[2],zsw[3]);
    #pragma unroll
    for (int nt=0;nt<3;nt++) gh2[nt] = mfma16(Awsh[nt], zsB, gh2[nt]);
    #pragma unroll
    for (int nt=0;nt<3;nt++) gi2[nt] = mfma16(Awsg[nt][0], sgB0, gi2[nt]);
    #pragma unroll
    for (int nt=0;nt<3;nt++) gi2[nt] = mfma16(Awsg[nt][1], sgB1, gi2[nt]);
    float zn[4];
    #pragma unroll
    for (int r=0;r<4;r++){
      float rg = fsigm(gi2[0][r] + gh2[0][r]);
      float zg = fsigm(gi2[1][r] + gh2[1][r]);
      float ng = ftanh(gi2[2][r] + rg*gh2[2][r]);
      float zt = (1.f-zg)*ng + zg*zs_r[r];
      float z2 = upd*zt + (1.f-upd)*zs_r[r];
      zs_r[r] = z2; zn[r] = z2;
    }
    {
      f32x4 o = (f32x4){zn[0],zn[1],zn[2],zn[3]};
      *(f32x4*)(out_zs + (rowT+t)*16 + lh*4) = o;
    }
    // T4: zs D->B (RNE, 4 bperm)
    {
      unsigned QS0=pkr(zn[0],zn[1]), QS1=pkr(zn[2],zn[3]);
      #pragma unroll
      for (int w=0;w<4;w++){
        int srcl = ((2*(lh&1) + (w>>1))<<4) + l15;
        unsigned v = bperm(srcl, (w&1)?QS1:QS0);
        zsw[w] = (lh<2) ? v : 0u;
      }
    }
  }
}

// ---------------- K3: MFMA decoder, 64 rows/block, fp32 in/out ----------------
__global__ __launch_bounds__(256) void k_dec(
  const float* __restrict__ izf, const float* __restrict__ izs,
  const float* __restrict__ de_w1, const float* __restrict__ de_b1,
  const float* __restrict__ de_w2, const float* __restrict__ de_b2,
  float* __restrict__ preds)
{
  __shared__ __align__(16) u16t s_a[64*64];
  __shared__ __align__(16) u16t s_h[64*256];
  const int tid = threadIdx.x;
  const int lane = tid & 63, wave = tid >> 6;
  const int l15 = lane & 15, lh = lane >> 4;
  const long row0 = (long)blockIdx.x * 64;

  { int row = tid >> 2, col = (tid & 3) << 3;
    bf16x8 v = ldw8(izf + (row0+row)*32 + col);
    *(bf16x8*)&s_a[row*64 + (col ^ ((row&7)<<3))] = v; }
  if (tid < 128){
    int row = tid >> 1, col = 32 + ((tid & 1) << 3);
    bf16x8 v = ldw8(izs + (row0+row)*16 + ((tid&1)<<3));
    *(bf16x8*)&s_a[row*64 + (col ^ ((row&7)<<3))] = v;
  } else {
    int t2 = tid - 128;
    int row = t2 >> 1, col = 48 + ((t2 & 1) << 3);
    bf16x8 v = zero8();
    *(bf16x8*)&s_a[row*64 + (col ^ ((row&7)<<3))] = v;
  }
  __syncthreads();

  const int wrow = wave*16;
  const int arow = wrow + l15;
  f32x4 acc[16];
  #pragma unroll
  for (int nt=0;nt<16;nt++){ float bv = de_b1[nt*16+l15]; acc[nt] = (f32x4){bv,bv,bv,bv}; }
  #pragma unroll
  for (int kt=0;kt<2;kt++){
    int acol = kt*32 + lh*8;
    bf16x8 af = *(const bf16x8*)&s_a[arow*64 + (acol ^ ((arow&7)<<3))];
    #pragma unroll
    for (int nt=0;nt<16;nt++){
      bf16x8 bw = zero8();
      if (!(kt==1 && lh>=2)) bw = ldw8(de_w1 + (nt*16+l15)*48 + acol);
      acc[nt] = mfma16(af, bw, acc[nt]);
    }
  }
  #pragma unroll
  for (int nt=0;nt<16;nt++){
    #pragma unroll
    for (int r=0;r<4;r++){
      int row = wrow + lh*4 + r; int col = nt*16 + l15;
      s_h[row*256 + (col ^ ((row&7)<<3))] = f2b(fgelu(acc[nt][r]));
    }
  }
  __syncthreads();
  f32x4 a2[16];
  #pragma unroll
  for (int nt=0;nt<16;nt++){ float bv = de_b2[nt*16+l15]; a2[nt] = (f32x4){bv,bv,bv,bv}; }
  #pragma unroll
  for (int kt=0;kt<8;kt++){
    int acol = kt*32 + lh*8;
    bf16x8 af = *(const bf16x8*)&s_h[arow*256 + (acol ^ ((arow&7)<<3))];
    #pragma unroll
    for (int nt=0;nt<16;nt++){
      bf16x8 bw = ldw8(de_w2 + (nt*16+l15)*256 + acol);
      a2[nt] = mfma16(af, bw, a2[nt]);
    }
  }
  #pragma unroll
  for (int nt=0;nt<16;nt++){
    #pragma unroll
    for (int r=0;r<4;r++){
      int row = wrow + lh*4 + r;
      preds[(row0+row)*256 + nt*16+l15] = a2[nt][r];
    }
  }
}

extern "C" void kernel_launch(void* const* d_in, const int* in_sizes, int n_in,
                              void* d_out, int out_size, void* d_ws, size_t ws_size,
                              hipStream_t stream)
{
  if (n_in < 25 || in_sizes[0] != (int)(Rn*256) || in_sizes[8] != 96*36 ||
      in_sizes[12] != 128*288 || in_sizes[20] != 256*48 || in_sizes[24] != 1)
    return;
  if (out_size != (int)(Rn*304))
    return;

  const float* states = (const float*)d_in[0];
  const float* actions= (const float*)d_in[1];
  const float* nfast  = (const float*)d_in[2];
  const float* nslow  = (const float*)d_in[3];
  const float* fe_w1  = (const float*)d_in[4];
  const float* fe_b1  = (const float*)d_in[5];
  const float* fe_w2  = (const float*)d_in[6];
  const float* fe_b2  = (const float*)d_in[7];
  const float* fg_wih = (const float*)d_in[8];
  const float* fg_whh = (const float*)d_in[9];
  const float* fg_bih = (const float*)d_in[10];
  const float* fg_bhh = (const float*)d_in[11];
  const float* se_w1  = (const float*)d_in[12];
  const float* se_b1  = (const float*)d_in[13];
  const float* se_w2  = (const float*)d_in[14];
  const float* se_b2  = (const float*)d_in[15];
  const float* sg_wih = (const float*)d_in[16];
  const float* sg_whh = (const float*)d_in[17];
  const float* sg_bih = (const float*)d_in[18];
  const float* sg_bhh = (const float*)d_in[19];
  const float* de_w1  = (const float*)d_in[20];
  const float* de_b1  = (const float*)d_in[21];
  const float* de_w2  = (const float*)d_in[22];
  const float* de_b2  = (const float*)d_in[23];
  const float* updp   = (const float*)d_in[24];

  // d_out is FP32: [preds | zf | zs] flat.
  float* preds = (float*)d_out;
  float* ozf = preds + Rn*256;
  float* ozs = ozf + Rn*32;

  // Scratch: zfn bf16 [Rn][32] + se1 bf16 [Rn][128] = Rn*320 bytes.
  size_t need = (size_t)Rn*320;
  u16t* ws_zfn; u16t* ws_se1;
  if (ws_size >= need){
    ws_zfn = (u16t*)d_ws;
    ws_se1 = ws_zfn + Rn*32;
  } else {
    ws_zfn = (u16t*)preds;   // alias inside preds fp32 region; k_dec overwrites after
    ws_se1 = ws_zfn + Rn*32;
  }

  k_pre<<<(int)(Rn/64), 256, 0, stream>>>(states, nfast,
      fe_w1, fe_b1, fe_w2, fe_b2, se_w1, se_b1, ws_zfn, ws_se1);
  k_rec<<<Bn/16, 64, 0, stream>>>(ws_zfn, ws_se1, actions, nslow,
      fg_wih, fg_whh, fg_bih, fg_bhh, se_w1, se_w2, se_b2,
      sg_wih, sg_whh, sg_bih, sg_bhh, updp, ozf, ozs);
  k_dec<<<(int)(Rn/64), 256, 0, stream>>>(ozf, ozs, de_w1, de_b1, de_w2, de_b2, preds);
}